// Round 3
// baseline (908.434 us; speedup 1.0000x reference)
//
#include <hip/hip_runtime.h>
#include <math.h>

#define B 8
#define C 256
#define CQ 32
#define H 128
#define W 128
#define P (H*W)   // 16384

typedef unsigned short ushortT;

__device__ __forceinline__ float bf2f(ushortT u) {
    union { unsigned int i; float f; } v; v.i = ((unsigned int)u) << 16; return v.f;
}
__device__ __forceinline__ ushortT f2bf(float f) {
    union { float f; unsigned int i; } v; v.f = f;
    unsigned int u = v.i;
    unsigned int r = (u + 0x7FFFu + ((u >> 16) & 1u)) >> 16;
    return (ushortT)r;
}

// ---------------- K1: projection q,k,v = W*x + b  (fp32 in, bf16 out) ----------------
// grid (P/128, 5, B), block 256. O_TILE=64, P_TILE=128, K_CHUNK=16.
__global__ __launch_bounds__(256) void proj_kernel(
    const float* __restrict__ x,
    const float* __restrict__ Wq, const float* __restrict__ bq,
    const float* __restrict__ Wk, const float* __restrict__ bk,
    const float* __restrict__ Wv, const float* __restrict__ bv,
    ushortT* __restrict__ qb, ushortT* __restrict__ kb, ushortT* __restrict__ vb)
{
    __shared__ float Ws[16][68];
    __shared__ float Xs[16][132];
    const int t  = threadIdx.x;
    const int p0 = blockIdx.x * 128;
    const int o0 = blockIdx.y * 64;
    const int b  = blockIdx.z;
    const int ty = t >> 4, tx = t & 15;

    float acc[4][8];
    #pragma unroll
    for (int i = 0; i < 4; i++)
        #pragma unroll
        for (int j = 0; j < 8; j++) acc[i][j] = 0.f;

    const int lo = t >> 2;         // 0..63
    const int kq = (t & 3) * 4;    // 0,4,8,12
    const int og = o0 + lo;
    const float* wrow;
    if (og < 32)       wrow = Wq + (size_t)og * C;
    else if (og < 64)  wrow = Wk + (size_t)(og - 32) * C;
    else               wrow = Wv + (size_t)(og - 64) * C;

    const float* xbase = x + ((size_t)b * C) * P + p0;

    for (int c0 = 0; c0 < C; c0 += 16) {
        float4 wv = *(const float4*)(wrow + c0 + kq);
        Ws[kq + 0][lo] = wv.x; Ws[kq + 1][lo] = wv.y;
        Ws[kq + 2][lo] = wv.z; Ws[kq + 3][lo] = wv.w;
        #pragma unroll
        for (int r = 0; r < 2; r++) {
            int qid = r * 256 + t;
            int kk = qid >> 5; int pq = (qid & 31) * 4;
            float4 xv = *(const float4*)(xbase + (size_t)(c0 + kk) * P + pq);
            *(float4*)&Xs[kk][pq] = xv;
        }
        __syncthreads();
        #pragma unroll
        for (int kk = 0; kk < 16; kk++) {
            float4 a  = *(const float4*)&Ws[kk][ty * 4];
            float4 b0 = *(const float4*)&Xs[kk][tx * 8];
            float4 b1 = *(const float4*)&Xs[kk][tx * 8 + 4];
            float av[4]  = {a.x, a.y, a.z, a.w};
            float bv8[8] = {b0.x, b0.y, b0.z, b0.w, b1.x, b1.y, b1.z, b1.w};
            #pragma unroll
            for (int i = 0; i < 4; i++)
                #pragma unroll
                for (int j = 0; j < 8; j++)
                    acc[i][j] = fmaf(av[i], bv8[j], acc[i][j]);
        }
        __syncthreads();
    }

    #pragma unroll
    for (int i = 0; i < 4; i++) {
        int og2 = o0 + ty * 4 + i;
        float bias; ushortT* dst;
        if (og2 < 32)      { bias = bq[og2];      dst = qb + ((size_t)(b * CQ + og2)) * P; }
        else if (og2 < 64) { bias = bk[og2 - 32]; dst = kb + ((size_t)(b * CQ + og2 - 32)) * P; }
        else               { bias = bv[og2 - 64]; dst = vb + ((size_t)(b * C  + og2 - 64)) * P; }
        ushort4 r0, r1;
        r0.x = f2bf(acc[i][0] + bias); r0.y = f2bf(acc[i][1] + bias);
        r0.z = f2bf(acc[i][2] + bias); r0.w = f2bf(acc[i][3] + bias);
        r1.x = f2bf(acc[i][4] + bias); r1.y = f2bf(acc[i][5] + bias);
        r1.z = f2bf(acc[i][6] + bias); r1.w = f2bf(acc[i][7] + bias);
        *(ushort4*)(dst + p0 + tx * 8)     = r0;
        *(ushort4*)(dst + p0 + tx * 8 + 4) = r1;
    }
}

// ---------------- K2: v (B,C,H,W) -> vto (B,W,C,H)  (bf16) ----------------
// grid (W/32, H/32, B*C), block (32,8)
__global__ void transpose_v_kernel(const ushortT* __restrict__ vb, ushortT* __restrict__ vt)
{
    __shared__ ushortT tile[32][33];
    const int w0 = blockIdx.x * 32, h0 = blockIdx.y * 32;
    const int bc = blockIdx.z;
    const int b = bc >> 8, c = bc & 255;
    const int txx = threadIdx.x;
    const ushortT* src = vb + (size_t)bc * P;
    for (int r = threadIdx.y; r < 32; r += 8)
        tile[r][txx] = src[(size_t)(h0 + r) * W + w0 + txx];
    __syncthreads();
    for (int r = threadIdx.y; r < 32; r += 8) {
        size_t didx = (((size_t)b * W + (w0 + r)) * C + c) * H + h0 + txx;
        vt[didx] = tile[txx][r];
    }
}

// ---------------- K3: eH logits (column) with diag mask (bf16 out) ----------------
// grid (W, B), block 256
__global__ __launch_bounds__(256) void eh_kernel(
    const ushortT* __restrict__ qb, const ushortT* __restrict__ kb, ushortT* __restrict__ att)
{
    __shared__ float Qs[CQ][132];
    __shared__ float Ks[CQ][132];
    const int t = threadIdx.x;
    const int w = blockIdx.x, b = blockIdx.y;
    #pragma unroll
    for (int i = 0; i < 16; i++) {
        int idx = i * 256 + t;
        int o = idx >> 7, h = idx & 127;
        size_t g = ((size_t)(b * CQ + o)) * P + (size_t)h * W + w;
        Qs[o][h] = bf2f(qb[g]);
        Ks[o][h] = bf2f(kb[g]);
    }
    __syncthreads();
    const int hb = t >> 5;           // 0..7
    const int gq = (t & 31) * 4;     // 0..124
    const float NEGINF = -__builtin_inff();
    for (int pass = 0; pass < 16; pass++) {
        int h = pass * 8 + hb;
        float qr[CQ];
        #pragma unroll
        for (int o = 0; o < CQ; o++) qr[o] = Qs[o][h];
        float4 a = {0.f, 0.f, 0.f, 0.f};
        #pragma unroll
        for (int o = 0; o < CQ; o++) {
            float4 kv = *(const float4*)&Ks[o][gq];
            a.x = fmaf(qr[o], kv.x, a.x);
            a.y = fmaf(qr[o], kv.y, a.y);
            a.z = fmaf(qr[o], kv.z, a.z);
            a.w = fmaf(qr[o], kv.w, a.w);
        }
        if (gq     == h) a.x = NEGINF;
        if (gq + 1 == h) a.y = NEGINF;
        if (gq + 2 == h) a.z = NEGINF;
        if (gq + 3 == h) a.w = NEGINF;
        ushort4 u;
        u.x = f2bf(a.x); u.y = f2bf(a.y); u.z = f2bf(a.z); u.w = f2bf(a.w);
        *(ushort4*)&att[((size_t)(b * P + h * W + w)) * 256 + gq] = u;
    }
}

// ---------------- K4: eW logits (row) (bf16 out) ----------------
// grid (H, B), block 256
__global__ __launch_bounds__(256) void ew_kernel(
    const ushortT* __restrict__ qb, const ushortT* __restrict__ kb, ushortT* __restrict__ att)
{
    __shared__ float Qs[CQ][132];
    __shared__ float Ks[CQ][132];
    const int t = threadIdx.x;
    const int h = blockIdx.x, b = blockIdx.y;
    #pragma unroll
    for (int r = 0; r < 4; r++) {
        int qd = r * 256 + t;
        int o = qd >> 5, wq = (qd & 31) * 4;
        size_t g = ((size_t)(b * CQ + o)) * P + (size_t)h * W + wq;
        ushort4 qv = *(const ushort4*)&qb[g];
        ushort4 kv = *(const ushort4*)&kb[g];
        Qs[o][wq + 0] = bf2f(qv.x); Qs[o][wq + 1] = bf2f(qv.y);
        Qs[o][wq + 2] = bf2f(qv.z); Qs[o][wq + 3] = bf2f(qv.w);
        Ks[o][wq + 0] = bf2f(kv.x); Ks[o][wq + 1] = bf2f(kv.y);
        Ks[o][wq + 2] = bf2f(kv.z); Ks[o][wq + 3] = bf2f(kv.w);
    }
    __syncthreads();
    const int wb = t >> 5;
    const int gq = (t & 31) * 4;
    for (int pass = 0; pass < 16; pass++) {
        int w = pass * 8 + wb;
        float qr[CQ];
        #pragma unroll
        for (int o = 0; o < CQ; o++) qr[o] = Qs[o][w];
        float4 a = {0.f, 0.f, 0.f, 0.f};
        #pragma unroll
        for (int o = 0; o < CQ; o++) {
            float4 kv = *(const float4*)&Ks[o][gq];
            a.x = fmaf(qr[o], kv.x, a.x);
            a.y = fmaf(qr[o], kv.y, a.y);
            a.z = fmaf(qr[o], kv.z, a.z);
            a.w = fmaf(qr[o], kv.w, a.w);
        }
        ushort4 u;
        u.x = f2bf(a.x); u.y = f2bf(a.y); u.z = f2bf(a.z); u.w = f2bf(a.w);
        *(ushort4*)&att[((size_t)(b * P + h * W + w)) * 256 + 128 + gq] = u;
    }
}

// ---------------- K5: joint softmax over 256, in place (bf16) ----------------
// grid (B*P/4), block 256 (4 waves x 64 lanes)
__global__ void softmax_kernel(ushortT* __restrict__ att)
{
    const int t = threadIdx.x;
    const int r = t >> 6, lane = t & 63;
    size_t pix = (size_t)blockIdx.x * 4 + r;
    ushort4* row = (ushort4*)(att + pix * 256);
    ushort4 u = row[lane];
    float v0 = bf2f(u.x), v1 = bf2f(u.y), v2 = bf2f(u.z), v3 = bf2f(u.w);
    float m = fmaxf(fmaxf(v0, v1), fmaxf(v2, v3));
    #pragma unroll
    for (int off = 32; off; off >>= 1) m = fmaxf(m, __shfl_xor(m, off));
    float e0 = __expf(v0 - m), e1 = __expf(v1 - m);
    float e2 = __expf(v2 - m), e3 = __expf(v3 - m);
    float s = e0 + e1 + e2 + e3;
    #pragma unroll
    for (int off = 32; off; off >>= 1) s += __shfl_xor(s, off);
    float inv = 1.f / s;
    u.x = f2bf(e0 * inv); u.y = f2bf(e1 * inv);
    u.z = f2bf(e2 * inv); u.w = f2bf(e3 * inv);
    row[lane] = u;
}

// ---------------- K6: outH = aH @ V_col, IN-PLACE into vto (B,W,C,H) ----------------
// grid (2, W, B), block 256. Block (c-half, w, b) reads only vto[b,w,c-half,:]
// and overwrites exactly that region at the end -> safe in-place reuse.
__global__ __launch_bounds__(256) void outh_kernel(
    ushortT* __restrict__ vt, const ushortT* __restrict__ att)
{
    __shared__ float As[32][132];
    __shared__ float Vs[32][132];
    const int t = threadIdx.x;
    const int c0 = blockIdx.x * 128;
    const int w = blockIdx.y, b = blockIdx.z;
    const int ty = t >> 4, tx = t & 15;
    float acc[8][8];
    #pragma unroll
    for (int i = 0; i < 8; i++)
        #pragma unroll
        for (int j = 0; j < 8; j++) acc[i][j] = 0.f;

    const int lr = t >> 3;        // 0..31
    const int gq = (t & 7) * 4;   // 0..28

    for (int g0 = 0; g0 < H; g0 += 32) {
        #pragma unroll
        for (int pass = 0; pass < 4; pass++) {
            int h = pass * 32 + lr;
            ushort4 a4 = *(const ushort4*)&att[((size_t)(b * P + h * W + w)) * 256 + g0 + gq];
            As[gq + 0][h] = bf2f(a4.x); As[gq + 1][h] = bf2f(a4.y);
            As[gq + 2][h] = bf2f(a4.z); As[gq + 3][h] = bf2f(a4.w);
            int c = pass * 32 + lr;
            ushort4 v4 = *(const ushort4*)&vt[(((size_t)b * W + w) * C + c0 + c) * H + g0 + gq];
            Vs[gq + 0][c] = bf2f(v4.x); Vs[gq + 1][c] = bf2f(v4.y);
            Vs[gq + 2][c] = bf2f(v4.z); Vs[gq + 3][c] = bf2f(v4.w);
        }
        __syncthreads();
        #pragma unroll
        for (int kk = 0; kk < 32; kk++) {
            float4 v0 = *(const float4*)&Vs[kk][ty * 8];
            float4 v1 = *(const float4*)&Vs[kk][ty * 8 + 4];
            float4 a0 = *(const float4*)&As[kk][tx * 8];
            float4 a1 = *(const float4*)&As[kk][tx * 8 + 4];
            float vv[8] = {v0.x, v0.y, v0.z, v0.w, v1.x, v1.y, v1.z, v1.w};
            float aa[8] = {a0.x, a0.y, a0.z, a0.w, a1.x, a1.y, a1.z, a1.w};
            #pragma unroll
            for (int i = 0; i < 8; i++)
                #pragma unroll
                for (int j = 0; j < 8; j++)
                    acc[i][j] = fmaf(vv[i], aa[j], acc[i][j]);
        }
        __syncthreads();
    }
    #pragma unroll
    for (int i = 0; i < 8; i++) {
        size_t base = (((size_t)b * W + w) * C + c0 + ty * 8 + i) * H + tx * 8;
        ushort4 r0, r1;
        r0.x = f2bf(acc[i][0]); r0.y = f2bf(acc[i][1]);
        r0.z = f2bf(acc[i][2]); r0.w = f2bf(acc[i][3]);
        r1.x = f2bf(acc[i][4]); r1.y = f2bf(acc[i][5]);
        r1.z = f2bf(acc[i][6]); r1.w = f2bf(acc[i][7]);
        *(ushort4*)&vt[base]     = r0;
        *(ushort4*)&vt[base + 4] = r1;
    }
}

// ---------------- K7: outW = aW @ V_row -> d_out (fp32, natural layout) ----------------
// grid (2, H, B), block 256
__global__ __launch_bounds__(256) void outw_kernel(
    const ushortT* __restrict__ vb, const ushortT* __restrict__ att, float* __restrict__ out)
{
    __shared__ float As[32][132];
    __shared__ float Vs[32][132];
    const int t = threadIdx.x;
    const int c0 = blockIdx.x * 128;
    const int h = blockIdx.y, b = blockIdx.z;
    const int ty = t >> 4, tx = t & 15;
    float acc[8][8];
    #pragma unroll
    for (int i = 0; i < 8; i++)
        #pragma unroll
        for (int j = 0; j < 8; j++) acc[i][j] = 0.f;

    const int lr = t >> 3;
    const int gq = (t & 7) * 4;

    for (int g0 = 0; g0 < W; g0 += 32) {
        #pragma unroll
        for (int pass = 0; pass < 4; pass++) {
            int wr = pass * 32 + lr;
            ushort4 a4 = *(const ushort4*)&att[((size_t)(b * P + h * W + wr)) * 256 + 128 + g0 + gq];
            As[gq + 0][wr] = bf2f(a4.x); As[gq + 1][wr] = bf2f(a4.y);
            As[gq + 2][wr] = bf2f(a4.z); As[gq + 3][wr] = bf2f(a4.w);
            int c = pass * 32 + lr;
            ushort4 v4 = *(const ushort4*)&vb[((size_t)(b * C + c0 + c)) * P + (size_t)h * W + g0 + gq];
            Vs[gq + 0][c] = bf2f(v4.x); Vs[gq + 1][c] = bf2f(v4.y);
            Vs[gq + 2][c] = bf2f(v4.z); Vs[gq + 3][c] = bf2f(v4.w);
        }
        __syncthreads();
        #pragma unroll
        for (int kk = 0; kk < 32; kk++) {
            float4 v0 = *(const float4*)&Vs[kk][ty * 8];
            float4 v1 = *(const float4*)&Vs[kk][ty * 8 + 4];
            float4 a0 = *(const float4*)&As[kk][tx * 8];
            float4 a1 = *(const float4*)&As[kk][tx * 8 + 4];
            float vv[8] = {v0.x, v0.y, v0.z, v0.w, v1.x, v1.y, v1.z, v1.w};
            float aa[8] = {a0.x, a0.y, a0.z, a0.w, a1.x, a1.y, a1.z, a1.w};
            #pragma unroll
            for (int i = 0; i < 8; i++)
                #pragma unroll
                for (int j = 0; j < 8; j++)
                    acc[i][j] = fmaf(vv[i], aa[j], acc[i][j]);
        }
        __syncthreads();
    }
    #pragma unroll
    for (int i = 0; i < 8; i++) {
        size_t base = ((size_t)(b * C + c0 + ty * 8 + i)) * P + (size_t)h * W + tx * 8;
        float4 r0 = {acc[i][0], acc[i][1], acc[i][2], acc[i][3]};
        float4 r1 = {acc[i][4], acc[i][5], acc[i][6], acc[i][7]};
        *(float4*)&out[base]     = r0;
        *(float4*)&out[base + 4] = r1;
    }
}

// ---------------- K8: out = gamma*(outW + outH) + x ----------------
// grid (W/32, H/32, B*C), block 256. Reads outH^T from vto (bf16).
__global__ void combine_kernel(
    const ushortT* __restrict__ oht, const float* __restrict__ x,
    const float* __restrict__ gamma, float* __restrict__ out)
{
    __shared__ ushortT tile[32][33];
    const int t = threadIdx.x;
    const int w0 = blockIdx.x * 32, h0 = blockIdx.y * 32;
    const int bc = blockIdx.z;
    const int b = bc >> 8, c = bc & 255;
    const int r = t >> 3, cq = (t & 7) * 4;

    // load outH_t tile: (w = w0+r, h = h0+cq+m), contiguous in h
    const ushortT* src = oht + (((size_t)b * W + w0 + r) * C + c) * H + h0 + cq;
    ushort4 v = *(const ushort4*)src;
    tile[r][cq + 0] = v.x; tile[r][cq + 1] = v.y;
    tile[r][cq + 2] = v.z; tile[r][cq + 3] = v.w;
    __syncthreads();

    const float g = gamma[0];
    size_t idx = ((size_t)bc) * P + (size_t)(h0 + r) * W + w0 + cq;
    float4 ov = *(const float4*)&out[idx];
    float4 xv = *(const float4*)&x[idx];
    float4 res;
    res.x = g * (ov.x + bf2f(tile[cq + 0][r])) + xv.x;
    res.y = g * (ov.y + bf2f(tile[cq + 1][r])) + xv.y;
    res.z = g * (ov.z + bf2f(tile[cq + 2][r])) + xv.z;
    res.w = g * (ov.w + bf2f(tile[cq + 3][r])) + xv.w;
    *(float4*)&out[idx] = res;
}

extern "C" void kernel_launch(void* const* d_in, const int* in_sizes, int n_in,
                              void* d_out, int out_size, void* d_ws, size_t ws_size,
                              hipStream_t stream)
{
    const float* x     = (const float*)d_in[0];
    const float* Wq    = (const float*)d_in[1];
    const float* bq    = (const float*)d_in[2];
    const float* Wk    = (const float*)d_in[3];
    const float* bk    = (const float*)d_in[4];
    const float* Wv    = (const float*)d_in[5];
    const float* bv    = (const float*)d_in[6];
    const float* gamma = (const float*)d_in[7];
    float* out = (float*)d_out;

    ushortT* ws = (ushortT*)d_ws;
    const size_t qk_sz  = (size_t)B * CQ * P;   //  4,194,304 bf16
    const size_t v_sz   = (size_t)B * C  * P;   // 33,554,432 bf16
    const size_t att_sz = (size_t)B * P * 256;  // 33,554,432 bf16

    ushortT* qb  = ws;
    ushortT* kb  = qb  + qk_sz;
    ushortT* vb  = kb  + qk_sz;
    ushortT* vto = vb  + v_sz;   // v transposed, then overwritten in-place with outH^T
    ushortT* att = vto + v_sz;

    const size_t needed_bytes = (2 * qk_sz + 2 * v_sz + att_sz) * sizeof(ushortT); // ~218 MB
    if (ws_size < needed_bytes) return;  // canary: zeros out -> absmax ~5.4

    proj_kernel<<<dim3(P / 128, 5, B), 256, 0, stream>>>(x, Wq, bq, Wk, bk, Wv, bv, qb, kb, vb);
    transpose_v_kernel<<<dim3(W / 32, H / 32, B * C), dim3(32, 8), 0, stream>>>(vb, vto);
    eh_kernel<<<dim3(W, B), 256, 0, stream>>>(qb, kb, att);
    ew_kernel<<<dim3(H, B), 256, 0, stream>>>(qb, kb, att);
    softmax_kernel<<<dim3(B * P / 4), 256, 0, stream>>>(att);
    outh_kernel<<<dim3(2, W, B), 256, 0, stream>>>(vto, att);
    outw_kernel<<<dim3(2, H, B), 256, 0, stream>>>(vb, att, out);
    combine_kernel<<<dim3(W / 32, H / 32, B * C), 256, 0, stream>>>(vto, x, gamma, out);
}

// Round 4
// 620.932 us; speedup vs baseline: 1.4630x; 1.4630x over previous
//
#include <hip/hip_runtime.h>
#include <math.h>

#define B 8
#define C 256
#define CQ 32
#define H 128
#define W 128
#define P (H*W)   // 16384

typedef unsigned short ushortT;
typedef __attribute__((ext_vector_type(8))) short bf16x8;
typedef __attribute__((ext_vector_type(4))) float f32x4;

__device__ __forceinline__ float bf2f(ushortT u) {
    union { unsigned int i; float f; } v; v.i = ((unsigned int)u) << 16; return v.f;
}
__device__ __forceinline__ ushortT f2bf(float f) {
    union { float f; unsigned int i; } v; v.f = f;
    unsigned int u = v.i;
    unsigned int r = (u + 0x7FFFu + ((u >> 16) & 1u)) >> 16;
    return (ushortT)r;
}

// ---------------- K0: pack Wq|Wk|Wv -> Wall bf16 [320][256], biases -> biasAll f32[320]
// grid 81 x 256. Blocks 0..79: weights; block 80: biases.
__global__ void pack_kernel(
    const float* __restrict__ Wq, const float* __restrict__ bq,
    const float* __restrict__ Wk, const float* __restrict__ bk,
    const float* __restrict__ Wv, const float* __restrict__ bv,
    ushortT* __restrict__ Wall, float* __restrict__ biasAll)
{
    const int t = threadIdx.x;
    if (blockIdx.x == 80) {
        for (int i = t; i < 320; i += 256) {
            float bv_;
            if (i < 32)       bv_ = bq[i];
            else if (i < 64)  bv_ = bk[i - 32];
            else              bv_ = bv[i - 64];
            biasAll[i] = bv_;
        }
        return;
    }
    int g = blockIdx.x * 256 + t;        // 0..20479, 4 elems each
    int idx4 = g * 4;
    int row = idx4 >> 8, col = idx4 & 255;
    const float* src;
    if (row < 32)       src = Wq + (size_t)row * 256 + col;
    else if (row < 64)  src = Wk + (size_t)(row - 32) * 256 + col;
    else                src = Wv + (size_t)(row - 64) * 256 + col;
    float4 v4 = *(const float4*)src;
    ushort4 u;
    u.x = f2bf(v4.x); u.y = f2bf(v4.y); u.z = f2bf(v4.z); u.w = f2bf(v4.w);
    *(ushort4*)(Wall + idx4) = u;
}

// ---------------- K1: projection via MFMA. grid (P/64, B), block 256 (4 waves).
// Each block: full 320 o-rows x 64 pixels. Wave w: o-range [w*80, w*80+80).
__global__ __launch_bounds__(256) void proj_mfma(
    const float* __restrict__ x, const ushortT* __restrict__ Wall,
    const float* __restrict__ biasAll,
    ushortT* __restrict__ qb, ushortT* __restrict__ kb, ushortT* __restrict__ vb)
{
    __shared__ ushortT Xs[64][264];   // [p][c], pad +8 => bank-uniform b128 reads
    const int t  = threadIdx.x;
    const int p0 = blockIdx.x * 64;
    const int b  = blockIdx.y;

    // stage X tile (fp32 -> bf16, transpose to [p][c])
    {
        const float* xb = x + (size_t)b * C * P + p0;
        int c = t >> 4, pq = (t & 15) * 4;
        #pragma unroll
        for (int i = 0; i < 16; i++) {
            int ci = c + i * 16;
            float4 v4 = *(const float4*)(xb + (size_t)ci * P + pq);
            Xs[pq + 0][ci] = f2bf(v4.x);
            Xs[pq + 1][ci] = f2bf(v4.y);
            Xs[pq + 2][ci] = f2bf(v4.z);
            Xs[pq + 3][ci] = f2bf(v4.w);
        }
    }
    __syncthreads();

    const int wid = t >> 6, lane = t & 63;
    const int lrow = lane & 15, lk = (lane >> 4) * 8;

    f32x4 acc[5][4];
    #pragma unroll
    for (int mi = 0; mi < 5; mi++)
        #pragma unroll
        for (int ni = 0; ni < 4; ni++)
            acc[mi][ni] = (f32x4){0.f, 0.f, 0.f, 0.f};

    const ushortT* wbase = Wall + (size_t)(wid * 80 + lrow) * 256 + lk;

    #pragma unroll
    for (int kk = 0; kk < 8; kk++) {
        bf16x8 a[5], bfr[4];
        #pragma unroll
        for (int mi = 0; mi < 5; mi++)
            a[mi] = *(const bf16x8*)(wbase + mi * 16 * 256 + kk * 32);
        #pragma unroll
        for (int ni = 0; ni < 4; ni++)
            bfr[ni] = *(const bf16x8*)&Xs[ni * 16 + lrow][kk * 32 + lk];
        #pragma unroll
        for (int mi = 0; mi < 5; mi++)
            #pragma unroll
            for (int ni = 0; ni < 4; ni++)
                acc[mi][ni] = __builtin_amdgcn_mfma_f32_16x16x32_bf16(
                    a[mi], bfr[ni], acc[mi][ni], 0, 0, 0);
    }

    // epilogue: D row = o = wid*80 + mi*16 + (lane>>4)*4 + reg, col = p = p0 + ni*16 + (lane&15)
    const int orow0 = wid * 80 + (lane >> 4) * 4;
    #pragma unroll
    for (int mi = 0; mi < 5; mi++) {
        #pragma unroll
        for (int reg = 0; reg < 4; reg++) {
            int o = orow0 + mi * 16 + reg;
            float bias = biasAll[o];
            ushortT* dst;
            if (o < 32)      dst = qb + ((size_t)(b * CQ + o)) * P;
            else if (o < 64) dst = kb + ((size_t)(b * CQ + o - 32)) * P;
            else             dst = vb + ((size_t)(b * C + o - 64)) * P;
            #pragma unroll
            for (int ni = 0; ni < 4; ni++)
                dst[p0 + ni * 16 + lrow] = f2bf(acc[mi][ni][reg] + bias);
        }
    }
}

// ---------------- K2: v (B,C,H,W) -> vto (B,W,C,H)  (bf16) ----------------
__global__ void transpose_v_kernel(const ushortT* __restrict__ vb, ushortT* __restrict__ vt)
{
    __shared__ ushortT tile[32][33];
    const int w0 = blockIdx.x * 32, h0 = blockIdx.y * 32;
    const int bc = blockIdx.z;
    const int b = bc >> 8, c = bc & 255;
    const int txx = threadIdx.x;
    const ushortT* src = vb + (size_t)bc * P;
    for (int r = threadIdx.y; r < 32; r += 8)
        tile[r][txx] = src[(size_t)(h0 + r) * W + w0 + txx];
    __syncthreads();
    for (int r = threadIdx.y; r < 32; r += 8) {
        size_t didx = (((size_t)b * W + (w0 + r)) * C + c) * H + h0 + txx;
        vt[didx] = tile[txx][r];
    }
}

// ---------------- K3: eH logits (column) with diag mask (bf16 out) ----------------
__global__ __launch_bounds__(256) void eh_kernel(
    const ushortT* __restrict__ qb, const ushortT* __restrict__ kb, ushortT* __restrict__ att)
{
    __shared__ float Qs[CQ][132];
    __shared__ float Ks[CQ][132];
    const int t = threadIdx.x;
    const int w = blockIdx.x, b = blockIdx.y;
    #pragma unroll
    for (int i = 0; i < 16; i++) {
        int idx = i * 256 + t;
        int o = idx >> 7, h = idx & 127;
        size_t g = ((size_t)(b * CQ + o)) * P + (size_t)h * W + w;
        Qs[o][h] = bf2f(qb[g]);
        Ks[o][h] = bf2f(kb[g]);
    }
    __syncthreads();
    const int hb = t >> 5;           // 0..7
    const int gq = (t & 31) * 4;     // 0..124
    const float NEGINF = -__builtin_inff();
    for (int pass = 0; pass < 16; pass++) {
        int h = pass * 8 + hb;
        float qr[CQ];
        #pragma unroll
        for (int o = 0; o < CQ; o++) qr[o] = Qs[o][h];
        float4 a = {0.f, 0.f, 0.f, 0.f};
        #pragma unroll
        for (int o = 0; o < CQ; o++) {
            float4 kv = *(const float4*)&Ks[o][gq];
            a.x = fmaf(qr[o], kv.x, a.x);
            a.y = fmaf(qr[o], kv.y, a.y);
            a.z = fmaf(qr[o], kv.z, a.z);
            a.w = fmaf(qr[o], kv.w, a.w);
        }
        if (gq     == h) a.x = NEGINF;
        if (gq + 1 == h) a.y = NEGINF;
        if (gq + 2 == h) a.z = NEGINF;
        if (gq + 3 == h) a.w = NEGINF;
        ushort4 u;
        u.x = f2bf(a.x); u.y = f2bf(a.y); u.z = f2bf(a.z); u.w = f2bf(a.w);
        *(ushort4*)&att[((size_t)(b * P + h * W + w)) * 256 + gq] = u;
    }
}

// ---------------- K4: eW logits (row) (bf16 out) ----------------
__global__ __launch_bounds__(256) void ew_kernel(
    const ushortT* __restrict__ qb, const ushortT* __restrict__ kb, ushortT* __restrict__ att)
{
    __shared__ float Qs[CQ][132];
    __shared__ float Ks[CQ][132];
    const int t = threadIdx.x;
    const int h = blockIdx.x, b = blockIdx.y;
    #pragma unroll
    for (int r = 0; r < 4; r++) {
        int qd = r * 256 + t;
        int o = qd >> 5, wq = (qd & 31) * 4;
        size_t g = ((size_t)(b * CQ + o)) * P + (size_t)h * W + wq;
        ushort4 qv = *(const ushort4*)&qb[g];
        ushort4 kv = *(const ushort4*)&kb[g];
        Qs[o][wq + 0] = bf2f(qv.x); Qs[o][wq + 1] = bf2f(qv.y);
        Qs[o][wq + 2] = bf2f(qv.z); Qs[o][wq + 3] = bf2f(qv.w);
        Ks[o][wq + 0] = bf2f(kv.x); Ks[o][wq + 1] = bf2f(kv.y);
        Ks[o][wq + 2] = bf2f(kv.z); Ks[o][wq + 3] = bf2f(kv.w);
    }
    __syncthreads();
    const int wb = t >> 5;
    const int gq = (t & 31) * 4;
    for (int pass = 0; pass < 16; pass++) {
        int w = pass * 8 + wb;
        float qr[CQ];
        #pragma unroll
        for (int o = 0; o < CQ; o++) qr[o] = Qs[o][w];
        float4 a = {0.f, 0.f, 0.f, 0.f};
        #pragma unroll
        for (int o = 0; o < CQ; o++) {
            float4 kv = *(const float4*)&Ks[o][gq];
            a.x = fmaf(qr[o], kv.x, a.x);
            a.y = fmaf(qr[o], kv.y, a.y);
            a.z = fmaf(qr[o], kv.z, a.z);
            a.w = fmaf(qr[o], kv.w, a.w);
        }
        ushort4 u;
        u.x = f2bf(a.x); u.y = f2bf(a.y); u.z = f2bf(a.z); u.w = f2bf(a.w);
        *(ushort4*)&att[((size_t)(b * P + h * W + w)) * 256 + 128 + gq] = u;
    }
}

// ---------------- K5: joint softmax over 256, in place (bf16) ----------------
__global__ void softmax_kernel(ushortT* __restrict__ att)
{
    const int t = threadIdx.x;
    const int r = t >> 6, lane = t & 63;
    size_t pix = (size_t)blockIdx.x * 4 + r;
    ushort4* row = (ushort4*)(att + pix * 256);
    ushort4 u = row[lane];
    float v0 = bf2f(u.x), v1 = bf2f(u.y), v2 = bf2f(u.z), v3 = bf2f(u.w);
    float m = fmaxf(fmaxf(v0, v1), fmaxf(v2, v3));
    #pragma unroll
    for (int off = 32; off; off >>= 1) m = fmaxf(m, __shfl_xor(m, off));
    float e0 = __expf(v0 - m), e1 = __expf(v1 - m);
    float e2 = __expf(v2 - m), e3 = __expf(v3 - m);
    float s = e0 + e1 + e2 + e3;
    #pragma unroll
    for (int off = 32; off; off >>= 1) s += __shfl_xor(s, off);
    float inv = 1.f / s;
    u.x = f2bf(e0 * inv); u.y = f2bf(e1 * inv);
    u.z = f2bf(e2 * inv); u.w = f2bf(e3 * inv);
    row[lane] = u;
}

// ---------------- K6: outH via MFMA, IN-PLACE into vto (B,W,C,H) ----------------
// grid (2, W, B), block 256 (2x2 waves). D[c][h] = sum_g V'[c][g] * attH[h][g].
__global__ __launch_bounds__(256) void outh_mfma(
    ushortT* __restrict__ vt, const ushortT* __restrict__ att)
{
    __shared__ ushortT Vs[128 * 128];
    __shared__ ushortT Ats[128 * 128];
    const int t = threadIdx.x;
    const int c0 = blockIdx.x * 128;
    const int w = blockIdx.y, b = blockIdx.z;

    const ushortT* vsrc = vt + (((size_t)b * W + w) * C + c0) * H;  // [c][g], contiguous
    const ushortT* asrc = att + ((size_t)b * P + w) * 256;           // row h: + h*(W*256), attH at +0
    #pragma unroll
    for (int i = 0; i < 8; i++) {
        int q = i * 256 + t;
        int row = q >> 4, c8 = (q & 15) * 8;
        int sidx = (row * 128 + c8) ^ ((row & 7) << 3);   // XOR swizzle (involution)
        *(bf16x8*)&Vs[sidx]  = *(const bf16x8*)(vsrc + (size_t)row * 128 + c8);
        *(bf16x8*)&Ats[sidx] = *(const bf16x8*)(asrc + (size_t)row * (W * 256) + c8);
    }
    __syncthreads();

    const int wid = t >> 6, lane = t & 63;
    const int wm = wid >> 1, wn = wid & 1;
    const int lrow = lane & 15, lk8 = (lane >> 4) * 8;

    f32x4 acc[4][4];
    #pragma unroll
    for (int mi = 0; mi < 4; mi++)
        #pragma unroll
        for (int ni = 0; ni < 4; ni++)
            acc[mi][ni] = (f32x4){0.f, 0.f, 0.f, 0.f};

    #pragma unroll
    for (int kk = 0; kk < 4; kk++) {
        bf16x8 a[4], bb[4];
        #pragma unroll
        for (int mi = 0; mi < 4; mi++) {
            int r = wm * 64 + mi * 16 + lrow;
            a[mi] = *(const bf16x8*)&Vs[(r * 128 + kk * 32 + lk8) ^ ((r & 7) << 3)];
        }
        #pragma unroll
        for (int ni = 0; ni < 4; ni++) {
            int r = wn * 64 + ni * 16 + lrow;
            bb[ni] = *(const bf16x8*)&Ats[(r * 128 + kk * 32 + lk8) ^ ((r & 7) << 3)];
        }
        #pragma unroll
        for (int mi = 0; mi < 4; mi++)
            #pragma unroll
            for (int ni = 0; ni < 4; ni++)
                acc[mi][ni] = __builtin_amdgcn_mfma_f32_16x16x32_bf16(
                    a[mi], bb[ni], acc[mi][ni], 0, 0, 0);
    }

    // write outH^T back in place: vt[b][w][c][h]
    ushortT* dst = vt + (((size_t)b * W + w) * C + c0) * H;
    #pragma unroll
    for (int mi = 0; mi < 4; mi++)
        #pragma unroll
        for (int reg = 0; reg < 4; reg++) {
            int cc = wm * 64 + mi * 16 + (lane >> 4) * 4 + reg;
            #pragma unroll
            for (int ni = 0; ni < 4; ni++) {
                int hh = wn * 64 + ni * 16 + lrow;
                dst[(size_t)cc * 128 + hh] = f2bf(acc[mi][ni][reg]);
            }
        }
}

// ---------------- K7: outW via MFMA -> d_out fp32 (B,C,H,W) ----------------
// grid (2, H, B), block 256 (2x2 waves). D[c][w] = sum_g V[c][g] * attW[w][g].
__global__ __launch_bounds__(256) void outw_mfma(
    const ushortT* __restrict__ vb, const ushortT* __restrict__ att, float* __restrict__ out)
{
    __shared__ ushortT Vs[128 * 128];
    __shared__ ushortT Ats[128 * 128];
    const int t = threadIdx.x;
    const int c0 = blockIdx.x * 128;
    const int h = blockIdx.y, b = blockIdx.z;

    const ushortT* vsrc = vb + ((size_t)(b * C + c0)) * P + (size_t)h * W;   // row c: +c*P
    const ushortT* asrc = att + ((size_t)b * P + (size_t)h * W) * 256 + 128; // row w: +w*256
    #pragma unroll
    for (int i = 0; i < 8; i++) {
        int q = i * 256 + t;
        int row = q >> 4, c8 = (q & 15) * 8;
        int sidx = (row * 128 + c8) ^ ((row & 7) << 3);
        *(bf16x8*)&Vs[sidx]  = *(const bf16x8*)(vsrc + (size_t)row * P + c8);
        *(bf16x8*)&Ats[sidx] = *(const bf16x8*)(asrc + (size_t)row * 256 + c8);
    }
    __syncthreads();

    const int wid = t >> 6, lane = t & 63;
    const int wm = wid >> 1, wn = wid & 1;
    const int lrow = lane & 15, lk8 = (lane >> 4) * 8;

    f32x4 acc[4][4];
    #pragma unroll
    for (int mi = 0; mi < 4; mi++)
        #pragma unroll
        for (int ni = 0; ni < 4; ni++)
            acc[mi][ni] = (f32x4){0.f, 0.f, 0.f, 0.f};

    #pragma unroll
    for (int kk = 0; kk < 4; kk++) {
        bf16x8 a[4], bb[4];
        #pragma unroll
        for (int mi = 0; mi < 4; mi++) {
            int r = wm * 64 + mi * 16 + lrow;
            a[mi] = *(const bf16x8*)&Vs[(r * 128 + kk * 32 + lk8) ^ ((r & 7) << 3)];
        }
        #pragma unroll
        for (int ni = 0; ni < 4; ni++) {
            int r = wn * 64 + ni * 16 + lrow;
            bb[ni] = *(const bf16x8*)&Ats[(r * 128 + kk * 32 + lk8) ^ ((r & 7) << 3)];
        }
        #pragma unroll
        for (int mi = 0; mi < 4; mi++)
            #pragma unroll
            for (int ni = 0; ni < 4; ni++)
                acc[mi][ni] = __builtin_amdgcn_mfma_f32_16x16x32_bf16(
                    a[mi], bb[ni], acc[mi][ni], 0, 0, 0);
    }

    #pragma unroll
    for (int mi = 0; mi < 4; mi++)
        #pragma unroll
        for (int reg = 0; reg < 4; reg++) {
            int cc = c0 + wm * 64 + mi * 16 + (lane >> 4) * 4 + reg;
            #pragma unroll
            for (int ni = 0; ni < 4; ni++) {
                int ww = wn * 64 + ni * 16 + lrow;
                out[((size_t)(b * C + cc)) * P + (size_t)h * W + ww] = acc[mi][ni][reg];
            }
        }
}

// ---------------- K8: out = gamma*(outW + outH) + x ----------------
__global__ void combine_kernel(
    const ushortT* __restrict__ oht, const float* __restrict__ x,
    const float* __restrict__ gamma, float* __restrict__ out)
{
    __shared__ ushortT tile[32][33];
    const int t = threadIdx.x;
    const int w0 = blockIdx.x * 32, h0 = blockIdx.y * 32;
    const int bc = blockIdx.z;
    const int b = bc >> 8, c = bc & 255;
    const int r = t >> 3, cq = (t & 7) * 4;

    const ushortT* src = oht + (((size_t)b * W + w0 + r) * C + c) * H + h0 + cq;
    ushort4 v = *(const ushort4*)src;
    tile[r][cq + 0] = v.x; tile[r][cq + 1] = v.y;
    tile[r][cq + 2] = v.z; tile[r][cq + 3] = v.w;
    __syncthreads();

    const float g = gamma[0];
    size_t idx = ((size_t)bc) * P + (size_t)(h0 + r) * W + w0 + cq;
    float4 ov = *(const float4*)&out[idx];
    float4 xv = *(const float4*)&x[idx];
    float4 res;
    res.x = g * (ov.x + bf2f(tile[cq + 0][r])) + xv.x;
    res.y = g * (ov.y + bf2f(tile[cq + 1][r])) + xv.y;
    res.z = g * (ov.z + bf2f(tile[cq + 2][r])) + xv.z;
    res.w = g * (ov.w + bf2f(tile[cq + 3][r])) + xv.w;
    *(float4*)&out[idx] = res;
}

extern "C" void kernel_launch(void* const* d_in, const int* in_sizes, int n_in,
                              void* d_out, int out_size, void* d_ws, size_t ws_size,
                              hipStream_t stream)
{
    const float* x     = (const float*)d_in[0];
    const float* Wq    = (const float*)d_in[1];
    const float* bq    = (const float*)d_in[2];
    const float* Wk    = (const float*)d_in[3];
    const float* bk    = (const float*)d_in[4];
    const float* Wv    = (const float*)d_in[5];
    const float* bv    = (const float*)d_in[6];
    const float* gamma = (const float*)d_in[7];
    float* out = (float*)d_out;

    ushortT* ws = (ushortT*)d_ws;
    const size_t qk_sz  = (size_t)B * CQ * P;   //  4,194,304 bf16
    const size_t v_sz   = (size_t)B * C  * P;   // 33,554,432 bf16
    const size_t att_sz = (size_t)B * P * 256;  // 33,554,432 bf16

    ushortT* qb  = ws;
    ushortT* kb  = qb  + qk_sz;
    ushortT* vb  = kb  + qk_sz;
    ushortT* vto = vb  + v_sz;   // v transposed, then overwritten in-place with outH^T
    ushortT* att = vto + v_sz;

    // scratch for packed weights lives in the att region (att is written later by eh/ew)
    ushortT* Wall   = att;                       // 81920 bf16 = 160 KB
    float*   biasAll = (float*)(att + 81920);    // 320 f32

    const size_t needed_bytes = (2 * qk_sz + 2 * v_sz + att_sz) * sizeof(ushortT); // ~218 MB
    if (ws_size < needed_bytes) return;  // canary: zeros out -> absmax ~5.4

    pack_kernel<<<dim3(81), 256, 0, stream>>>(Wq, bq, Wk, bk, Wv, bv, Wall, biasAll);
    proj_mfma<<<dim3(P / 64, B), 256, 0, stream>>>(x, Wall, biasAll, qb, kb, vb);
    transpose_v_kernel<<<dim3(W / 32, H / 32, B * C), dim3(32, 8), 0, stream>>>(vb, vto);
    eh_kernel<<<dim3(W, B), 256, 0, stream>>>(qb, kb, att);
    ew_kernel<<<dim3(H, B), 256, 0, stream>>>(qb, kb, att);
    softmax_kernel<<<dim3(B * P / 4), 256, 0, stream>>>(att);
    outh_mfma<<<dim3(2, W, B), 256, 0, stream>>>(vto, att);
    outw_mfma<<<dim3(2, H, B), 256, 0, stream>>>(vb, att, out);
    combine_kernel<<<dim3(W / 32, H / 32, B * C), 256, 0, stream>>>(vto, x, gamma, out);
}

// Round 8
// 525.122 us; speedup vs baseline: 1.7299x; 1.1825x over previous
//
#include <hip/hip_runtime.h>
#include <math.h>

#define B 8
#define C 256
#define CQ 32
#define H 128
#define W 128
#define P (H*W)   // 16384

typedef unsigned short ushortT;
typedef __attribute__((ext_vector_type(8))) short bf16x8;
typedef __attribute__((ext_vector_type(4))) float f32x4;

__device__ __forceinline__ float bf2f(ushortT u) {
    union { unsigned int i; float f; } v; v.i = ((unsigned int)u) << 16; return v.f;
}
__device__ __forceinline__ ushortT f2bf(float f) {
    union { float f; unsigned int i; } v; v.f = f;
    unsigned int u = v.i;
    unsigned int r = (u + 0x7FFFu + ((u >> 16) & 1u)) >> 16;
    return (ushortT)r;
}

// ---------------- K0: pack W into fragment-major bf16 + biases ----------------
// Wfrag layout: frag id f = (wid*8+kk)*5+mi; element (f*64 + lane)*8 + j
//   maps to W[(wid*5+mi)*16 + (lane&15)][kk*32 + (lane>>4)*8 + j]
// grid 41 x 256 (blocks 0..39 weights, block 40 biases)
__global__ void pack_kernel(
    const float* __restrict__ Wq, const float* __restrict__ bq,
    const float* __restrict__ Wk, const float* __restrict__ bk,
    const float* __restrict__ Wv, const float* __restrict__ bv,
    ushortT* __restrict__ Wfrag, float* __restrict__ biasAll)
{
    const int t = threadIdx.x;
    if (blockIdx.x == 40) {
        for (int i = t; i < 320; i += 256) {
            float bv_;
            if (i < 32)       bv_ = bq[i];
            else if (i < 64)  bv_ = bk[i - 32];
            else              bv_ = bv[i - 64];
            biasAll[i] = bv_;
        }
        return;
    }
    int g = blockIdx.x * 256 + t;          // 0..10239
    int f = g >> 6, lane = g & 63;
    int widp = f / 40, rem = f % 40;
    int kk = rem / 5, mi = rem % 5;
    int orow = (widp * 5 + mi) * 16 + (lane & 15);
    int col  = kk * 32 + (lane >> 4) * 8;
    const float* src;
    if (orow < 32)      src = Wq + (size_t)orow * C + col;
    else if (orow < 64) src = Wk + (size_t)(orow - 32) * C + col;
    else                src = Wv + (size_t)(orow - 64) * C + col;
    float4 v0 = *(const float4*)src;
    float4 v1 = *(const float4*)(src + 4);
    bf16x8 o;
    o[0] = (short)f2bf(v0.x); o[1] = (short)f2bf(v0.y);
    o[2] = (short)f2bf(v0.z); o[3] = (short)f2bf(v0.w);
    o[4] = (short)f2bf(v1.x); o[5] = (short)f2bf(v1.y);
    o[6] = (short)f2bf(v1.z); o[7] = (short)f2bf(v1.w);
    *(bf16x8*)(Wfrag + (size_t)g * 8) = o;
}

// ---------------- K0b: x (B,C,H,W) fp32 -> xt (B,P,C) bf16 ----------------
// grid (P/32, C/64, B), block 256. Load: 8 passes (1 elem/thread);
// store: ONE pass (8 elems/thread) -- 32 px x 64 c tile exactly.
__global__ void xt_kernel(const float* __restrict__ x, ushortT* __restrict__ xt)
{
    __shared__ ushortT tile[32][72];
    const int t = threadIdx.x;
    const int p0 = blockIdx.x * 32, c0 = blockIdx.y * 64;
    const int b = blockIdx.z;
    #pragma unroll
    for (int j = 0; j < 8; j++) {
        int q = j * 256 + t;
        int cr = q >> 5, pc = q & 31;
        tile[pc][cr] = f2bf(x[((size_t)b * C + c0 + cr) * P + p0 + pc]);
    }
    __syncthreads();
    {
        int pr = t >> 3, c8 = (t & 7) * 8;   // 32 rows x 8 chunks = 256 threads
        bf16x8 v;
        #pragma unroll
        for (int i = 0; i < 8; i++) v[i] = (short)tile[pr][c8 + i];
        *(bf16x8*)&xt[((size_t)b * P + p0 + pr) * C + c0 + c8] = v;
    }
}

// ---------------- K1: proj via MFMA v3 ----------------
// grid (P/128, B), block 256 (4 waves). BM=320 (wave: 80 rows), BN=128, K=256.
// q,k written transposed (b,p,32); v natural (b,c,p).
__global__ __launch_bounds__(256, 2) void proj_mfma(
    const ushortT* __restrict__ xt, const ushortT* __restrict__ Wfrag,
    const float* __restrict__ biasAll,
    ushortT* __restrict__ qt, ushortT* __restrict__ kt, ushortT* __restrict__ vb)
{
    __shared__ ushortT smem[32768];   // 64 KB: Xs (staged X), later S epilogue
    const int t = threadIdx.x;
    const int p0 = blockIdx.x * 128;
    const int b = blockIdx.y;
    const int wid = t >> 6, lane = t & 63;
    const int lrow = lane & 15, lk8 = (lane >> 4) * 8;
    const int hi4 = (lane >> 4) * 4;

    // stage Xs[px][c] bf16 with XOR swizzle (both sides)
    {
        const ushortT* xtb = xt + ((size_t)b * P + p0) * 256;
        #pragma unroll
        for (int j = 0; j < 16; j++) {
            int q = j * 256 + t;
            int off = q * 8;
            int px = off >> 8, cu = off & 255;
            bf16x8 val = *(const bf16x8*)(xtb + (size_t)px * 256 + cu);
            *(bf16x8*)&smem[px * 256 + (cu ^ ((px & 7) << 3))] = val;
        }
    }
    __syncthreads();

    f32x4 acc[5][8];
    #pragma unroll
    for (int mi = 0; mi < 5; mi++)
        #pragma unroll
        for (int ni = 0; ni < 8; ni++)
            acc[mi][ni] = (f32x4){0.f, 0.f, 0.f, 0.f};

    const int sw = (lrow & 7) << 3;   // lane-constant read swizzle
    #pragma unroll 1
    for (int kk = 0; kk < 8; kk++) {
        bf16x8 a[5], bb[8];
        #pragma unroll
        for (int mi = 0; mi < 5; mi++)
            a[mi] = *(const bf16x8*)(Wfrag +
                ((size_t)(((wid * 8 + kk) * 5 + mi) * 64 + lane) << 3));
        #pragma unroll
        for (int ni = 0; ni < 8; ni++)
            bb[ni] = *(const bf16x8*)&smem[(ni * 16 + lrow) * 256 +
                ((kk * 32 + lk8) ^ sw)];
        #pragma unroll
        for (int mi = 0; mi < 5; mi++)
            #pragma unroll
            for (int ni = 0; ni < 8; ni++)
                acc[mi][ni] = __builtin_amdgcn_mfma_f32_16x16x32_bf16(
                    a[mi], bb[ni], acc[mi][ni], 0, 0, 0);
    }
    __syncthreads();   // before smem reuse

    // epilogue: two phases of 160 o-rows via LDS stage S[160][136]
    ushortT* S = smem;
    for (int ph = 0; ph < 2; ph++) {
        if ((wid >> 1) == ph) {
            #pragma unroll
            for (int mi = 0; mi < 5; mi++)
                #pragma unroll
                for (int reg = 0; reg < 4; reg++) {
                    int o = wid * 80 + mi * 16 + hi4 + reg;
                    int ol = o - ph * 160;
                    float bias = biasAll[o];
                    #pragma unroll
                    for (int ni = 0; ni < 8; ni++)
                        S[ol * 136 + ni * 16 + lrow] = f2bf(acc[mi][ni][reg] + bias);
                }
        }
        __syncthreads();
        if (ph == 0) {
            // q rows 0..31 and k rows 32..63 -> transposed (b,p,32)
            {
                int px = t >> 1, oh = (t & 1) * 16;
                size_t pixbase = ((size_t)b * P + p0 + px) * 32 + oh;
                bf16x8 q0, q1, k0, k1;
                #pragma unroll
                for (int i = 0; i < 8; i++) {
                    q0[i] = (short)S[(oh + i) * 136 + px];
                    q1[i] = (short)S[(oh + 8 + i) * 136 + px];
                    k0[i] = (short)S[(32 + oh + i) * 136 + px];
                    k1[i] = (short)S[(32 + oh + 8 + i) * 136 + px];
                }
                *(bf16x8*)&qt[pixbase]     = q0;
                *(bf16x8*)&qt[pixbase + 8] = q1;
                *(bf16x8*)&kt[pixbase]     = k0;
                *(bf16x8*)&kt[pixbase + 8] = k1;
            }
            // v rows 64..159 -> c = 0..95 natural
            #pragma unroll
            for (int j = 0; j < 6; j++) {
                int q = j * 256 + t;
                int row = q >> 4, c8 = (q & 15) * 8;
                bf16x8 v = *(const bf16x8*)&S[(64 + row) * 136 + c8];
                *(bf16x8*)&vb[((size_t)b * C + row) * P + p0 + c8] = v;
            }
        } else {
            // o 160..319 -> v c = 96..255
            #pragma unroll
            for (int j = 0; j < 10; j++) {
                int q = j * 256 + t;
                int row = q >> 4, c8 = (q & 15) * 8;
                bf16x8 v = *(const bf16x8*)&S[row * 136 + c8];
                *(bf16x8*)&vb[((size_t)b * C + 96 + row) * P + p0 + c8] = v;
            }
        }
        __syncthreads();
    }
}

// ---------------- K2: v (B,C,H,W) -> vto (B,W,C,H)  (bf16) ----------------
__global__ void transpose_v_kernel(const ushortT* __restrict__ vb, ushortT* __restrict__ vt)
{
    __shared__ ushortT tile[32][33];
    const int w0 = blockIdx.x * 32, h0 = blockIdx.y * 32;
    const int bc = blockIdx.z;
    const int b = bc >> 8, c = bc & 255;
    const int txx = threadIdx.x;
    const ushortT* src = vb + (size_t)bc * P;
    for (int r = threadIdx.y; r < 32; r += 8)
        tile[r][txx] = src[(size_t)(h0 + r) * W + w0 + txx];
    __syncthreads();
    for (int r = threadIdx.y; r < 32; r += 8) {
        size_t didx = (((size_t)b * W + (w0 + r)) * C + c) * H + h0 + txx;
        vt[didx] = tile[txx][r];
    }
}

// ---------------- K3: eH logits via MFMA (K=32, single step), diag mask ----------------
// grid (W, B), block 256 (4 waves, each 32 h x 128 g)
__global__ __launch_bounds__(256) void eh_mfma(
    const ushortT* __restrict__ qt, const ushortT* __restrict__ kt, ushortT* __restrict__ att)
{
    __shared__ ushortT S[128 * 136];
    const int t = threadIdx.x;
    const int w = blockIdx.x, b = blockIdx.y;
    const int wid = t >> 6, lane = t & 63;
    const int lrow = lane & 15, lk8 = (lane >> 4) * 8;
    const int hi4 = (lane >> 4) * 4;
    const ushortT* qtb = qt + (size_t)b * P * 32;
    const ushortT* ktb = kt + (size_t)b * P * 32;

    bf16x8 a[2], bb[8];
    #pragma unroll
    for (int mi = 0; mi < 2; mi++) {
        int h = wid * 32 + mi * 16 + lrow;
        a[mi] = *(const bf16x8*)&qtb[((size_t)(h * W + w)) * 32 + lk8];
    }
    #pragma unroll
    for (int ni = 0; ni < 8; ni++) {
        int g = ni * 16 + lrow;
        bb[ni] = *(const bf16x8*)&ktb[((size_t)(g * W + w)) * 32 + lk8];
    }
    f32x4 acc[2][8];
    #pragma unroll
    for (int mi = 0; mi < 2; mi++)
        #pragma unroll
        for (int ni = 0; ni < 8; ni++)
            acc[mi][ni] = __builtin_amdgcn_mfma_f32_16x16x32_bf16(
                a[mi], bb[ni], (f32x4){0.f, 0.f, 0.f, 0.f}, 0, 0, 0);

    #pragma unroll
    for (int mi = 0; mi < 2; mi++)
        #pragma unroll
        for (int reg = 0; reg < 4; reg++) {
            int h = wid * 32 + mi * 16 + hi4 + reg;
            #pragma unroll
            for (int ni = 0; ni < 8; ni++) {
                int g = ni * 16 + lrow;
                S[h * 136 + g] = (g == h) ? (ushortT)0xFF80 : f2bf(acc[mi][ni][reg]);
            }
        }
    __syncthreads();
    #pragma unroll
    for (int j = 0; j < 8; j++) {
        int q = j * 256 + t;
        int row = q >> 4, c8 = (q & 15) * 8;
        bf16x8 v = *(const bf16x8*)&S[row * 136 + c8];
        *(bf16x8*)&att[((size_t)b * P + row * W + w) * 256 + c8] = v;
    }
}

// ---------------- K4: eW logits via MFMA + fused joint softmax ----------------
// grid (H, B), block 256. eW kept in LDS (bf16); eH read back from att; writes
// the softmaxed full 256-row in place.
__global__ __launch_bounds__(256) void ew_sm(
    const ushortT* __restrict__ qt, const ushortT* __restrict__ kt, ushortT* __restrict__ att)
{
    __shared__ ushortT eWs[128 * 136];   // 34.8 KB bf16
    const int t = threadIdx.x;
    const int h = blockIdx.x, b = blockIdx.y;
    const int wid = t >> 6, lane = t & 63;
    const int lrow = lane & 15, lk8 = (lane >> 4) * 8;
    const int hi4 = (lane >> 4) * 4;
    const ushortT* qtb = qt + (size_t)b * P * 32;
    const ushortT* ktb = kt + (size_t)b * P * 32;

    bf16x8 a[2], bb[8];
    #pragma unroll
    for (int mi = 0; mi < 2; mi++) {
        int wr = wid * 32 + mi * 16 + lrow;
        a[mi] = *(const bf16x8*)&qtb[((size_t)(h * W + wr)) * 32 + lk8];
    }
    #pragma unroll
    for (int ni = 0; ni < 8; ni++) {
        int g = ni * 16 + lrow;
        bb[ni] = *(const bf16x8*)&ktb[((size_t)(h * W + g)) * 32 + lk8];
    }
    f32x4 acc[2][8];
    #pragma unroll
    for (int mi = 0; mi < 2; mi++)
        #pragma unroll
        for (int ni = 0; ni < 8; ni++)
            acc[mi][ni] = __builtin_amdgcn_mfma_f32_16x16x32_bf16(
                a[mi], bb[ni], (f32x4){0.f, 0.f, 0.f, 0.f}, 0, 0, 0);

    #pragma unroll
    for (int mi = 0; mi < 2; mi++)
        #pragma unroll
        for (int reg = 0; reg < 4; reg++) {
            int wl = wid * 32 + mi * 16 + hi4 + reg;
            #pragma unroll
            for (int ni = 0; ni < 8; ni++)
                eWs[wl * 136 + ni * 16 + lrow] = f2bf(acc[mi][ni][reg]);
        }
    __syncthreads();

    // softmax: wave per row, 32 rows per wave; lanes<32 handle eH (from att),
    // lanes>=32 handle eW (from LDS)
    for (int r = 0; r < 32; r++) {
        int wl = wid * 32 + r;
        size_t pix = (size_t)b * P + h * W + wl;
        ushortT* rowp = att + pix * 256;
        float v0, v1, v2, v3;
        if (lane < 32) {
            ushort4 u = *(const ushort4*)&rowp[lane * 4];
            v0 = bf2f(u.x); v1 = bf2f(u.y); v2 = bf2f(u.z); v3 = bf2f(u.w);
        } else {
            ushort4 u = *(const ushort4*)&eWs[wl * 136 + (lane - 32) * 4];
            v0 = bf2f(u.x); v1 = bf2f(u.y); v2 = bf2f(u.z); v3 = bf2f(u.w);
        }
        float m = fmaxf(fmaxf(v0, v1), fmaxf(v2, v3));
        #pragma unroll
        for (int off = 32; off; off >>= 1) m = fmaxf(m, __shfl_xor(m, off));
        float e0 = __expf(v0 - m), e1 = __expf(v1 - m);
        float e2 = __expf(v2 - m), e3 = __expf(v3 - m);
        float s = e0 + e1 + e2 + e3;
        #pragma unroll
        for (int off = 32; off; off >>= 1) s += __shfl_xor(s, off);
        float inv = 1.f / s;
        ushort4 o;
        o.x = f2bf(e0 * inv); o.y = f2bf(e1 * inv);
        o.z = f2bf(e2 * inv); o.w = f2bf(e3 * inv);
        *(ushort4*)&rowp[lane * 4] = o;
    }
}

// ---------------- K6: outH via MFMA, IN-PLACE into vto (B,W,C,H) ----------------
// grid (2, W, B), block 256 (2x2 waves)
__global__ __launch_bounds__(256) void outh_mfma(
    ushortT* __restrict__ vt, const ushortT* __restrict__ att)
{
    __shared__ ushortT smem[32768];
    ushortT* Vs  = smem;
    ushortT* Ats = smem + 16384;
    const int t = threadIdx.x;
    const int c0 = blockIdx.x * 128;
    const int w = blockIdx.y, b = blockIdx.z;

    const ushortT* vsrc = vt + (((size_t)b * W + w) * C + c0) * H;
    const ushortT* asrc = att + ((size_t)b * P + w) * 256;
    #pragma unroll
    for (int i = 0; i < 8; i++) {
        int q = i * 256 + t;
        int row = q >> 4, c8 = (q & 15) * 8;
        int sidx = (row * 128 + c8) ^ ((row & 7) << 3);
        *(bf16x8*)&Vs[sidx]  = *(const bf16x8*)(vsrc + (size_t)row * 128 + c8);
        *(bf16x8*)&Ats[sidx] = *(const bf16x8*)(asrc + (size_t)row * (W * 256) + c8);
    }
    __syncthreads();

    const int wid = t >> 6, lane = t & 63;
    const int wm = wid >> 1, wn = wid & 1;
    const int lrow = lane & 15, lk8 = (lane >> 4) * 8;
    const int hi4 = (lane >> 4) * 4;

    f32x4 acc[4][4];
    #pragma unroll
    for (int mi = 0; mi < 4; mi++)
        #pragma unroll
        for (int ni = 0; ni < 4; ni++)
            acc[mi][ni] = (f32x4){0.f, 0.f, 0.f, 0.f};

    #pragma unroll
    for (int kk = 0; kk < 4; kk++) {
        bf16x8 a[4], bb[4];
        #pragma unroll
        for (int mi = 0; mi < 4; mi++) {
            int r = wm * 64 + mi * 16 + lrow;
            a[mi] = *(const bf16x8*)&Vs[(r * 128 + kk * 32 + lk8) ^ ((r & 7) << 3)];
        }
        #pragma unroll
        for (int ni = 0; ni < 4; ni++) {
            int r = wn * 64 + ni * 16 + lrow;
            bb[ni] = *(const bf16x8*)&Ats[(r * 128 + kk * 32 + lk8) ^ ((r & 7) << 3)];
        }
        #pragma unroll
        for (int mi = 0; mi < 4; mi++)
            #pragma unroll
            for (int ni = 0; ni < 4; ni++)
                acc[mi][ni] = __builtin_amdgcn_mfma_f32_16x16x32_bf16(
                    a[mi], bb[ni], acc[mi][ni], 0, 0, 0);
    }
    __syncthreads();

    // staged epilogue: S[128][136] bf16, then coalesced 256B-row stores
    ushortT* S = smem;
    #pragma unroll
    for (int mi = 0; mi < 4; mi++)
        #pragma unroll
        for (int reg = 0; reg < 4; reg++) {
            int cl = wm * 64 + mi * 16 + hi4 + reg;
            #pragma unroll
            for (int ni = 0; ni < 4; ni++) {
                int hl = wn * 64 + ni * 16 + lrow;
                S[cl * 136 + hl] = f2bf(acc[mi][ni][reg]);
            }
        }
    __syncthreads();
    ushortT* dst = vt + (((size_t)b * W + w) * C + c0) * H;
    #pragma unroll
    for (int j = 0; j < 8; j++) {
        int q = j * 256 + t;
        int row = q >> 4, c8 = (q & 15) * 8;
        *(bf16x8*)&dst[(size_t)row * H + c8] = *(const bf16x8*)&S[row * 136 + c8];
    }
}

// ---------------- K7: outW via MFMA -> d_out fp32 (B,C,H,W) ----------------
// grid (2, H, B), block 256
__global__ __launch_bounds__(256) void outw_mfma(
    const ushortT* __restrict__ vb, const ushortT* __restrict__ att, float* __restrict__ out)
{
    __shared__ ushortT smem[32768];
    ushortT* Vs  = smem;
    ushortT* Ats = smem + 16384;
    const int t = threadIdx.x;
    const int c0 = blockIdx.x * 128;
    const int h = blockIdx.y, b = blockIdx.z;

    const ushortT* vsrc = vb + ((size_t)(b * C + c0)) * P + (size_t)h * W;
    const ushortT* asrc = att + ((size_t)b * P + (size_t)h * W) * 256 + 128;
    #pragma unroll
    for (int i = 0; i < 8; i++) {
        int q = i * 256 + t;
        int row = q >> 4, c8 = (q & 15) * 8;
        int sidx = (row * 128 + c8) ^ ((row & 7) << 3);
        *(bf16x8*)&Vs[sidx]  = *(const bf16x8*)(vsrc + (size_t)row * P + c8);
        *(bf16x8*)&Ats[sidx] = *(const bf16x8*)(asrc + (size_t)row * 256 + c8);
    }
    __syncthreads();

    const int wid = t >> 6, lane = t & 63;
    const int wm = wid >> 1, wn = wid & 1;
    const int lrow = lane & 15, lk8 = (lane >> 4) * 8;
    const int hi4 = (lane >> 4) * 4;

    f32x4 acc[4][4];
    #pragma unroll
    for (int mi = 0; mi < 4; mi++)
        #pragma unroll
        for (int ni = 0; ni < 4; ni++)
            acc[mi][ni] = (f32x4){0.f, 0.f, 0.f, 0.f};

    #pragma unroll
    for (int kk = 0; kk < 4; kk++) {
        bf16x8 a[4], bb[4];
        #pragma unroll
        for (int mi = 0; mi < 4; mi++) {
            int r = wm * 64 + mi * 16 + lrow;
            a[mi] = *(const bf16x8*)&Vs[(r * 128 + kk * 32 + lk8) ^ ((r & 7) << 3)];
        }
        #pragma unroll
        for (int ni = 0; ni < 4; ni++) {
            int r = wn * 64 + ni * 16 + lrow;
            bb[ni] = *(const bf16x8*)&Ats[(r * 128 + kk * 32 + lk8) ^ ((r & 7) << 3)];
        }
        #pragma unroll
        for (int mi = 0; mi < 4; mi++)
            #pragma unroll
            for (int ni = 0; ni < 4; ni++)
                acc[mi][ni] = __builtin_amdgcn_mfma_f32_16x16x32_bf16(
                    a[mi], bb[ni], acc[mi][ni], 0, 0, 0);
    }
    __syncthreads();

    // staged epilogue fp32: two phases of 64 c-rows, S[64][132] f32
    float* S = (float*)smem;
    for (int ph = 0; ph < 2; ph++) {
        if (wm == ph) {
            #pragma unroll
            for (int mi = 0; mi < 4; mi++)
                #pragma unroll
                for (int reg = 0; reg < 4; reg++) {
                    int cl = mi * 16 + hi4 + reg;   // local to phase
                    #pragma unroll
                    for (int ni = 0; ni < 4; ni++) {
                        int hl = wn * 64 + ni * 16 + lrow;
                        S[cl * 132 + hl] = acc[mi][ni][reg];
                    }
                }
        }
        __syncthreads();
        #pragma unroll
        for (int j = 0; j < 8; j++) {
            int q = j * 256 + t;
            int row = q >> 5, f4 = (q & 31) * 4;
            float4 v = *(const float4*)&S[row * 132 + f4];
            *(float4*)&out[((size_t)b * C + c0 + ph * 64 + row) * P + (size_t)h * W + f4] = v;
        }
        __syncthreads();
    }
}

// ---------------- K8: out = gamma*(outW + outH) + x ----------------
__global__ void combine_kernel(
    const ushortT* __restrict__ oht, const float* __restrict__ x,
    const float* __restrict__ gamma, float* __restrict__ out)
{
    __shared__ ushortT tile[32][33];
    const int t = threadIdx.x;
    const int w0 = blockIdx.x * 32, h0 = blockIdx.y * 32;
    const int bc = blockIdx.z;
    const int b = bc >> 8, c = bc & 255;
    const int r = t >> 3, cq = (t & 7) * 4;

    const ushortT* src = oht + (((size_t)b * W + w0 + r) * C + c) * H + h0 + cq;
    ushort4 v = *(const ushort4*)src;
    tile[r][cq + 0] = v.x; tile[r][cq + 1] = v.y;
    tile[r][cq + 2] = v.z; tile[r][cq + 3] = v.w;
    __syncthreads();

    const float g = gamma[0];
    size_t idx = ((size_t)bc) * P + (size_t)(h0 + r) * W + w0 + cq;
    float4 ov = *(const float4*)&out[idx];
    float4 xv = *(const float4*)&x[idx];
    float4 res;
    res.x = g * (ov.x + bf2f(tile[cq + 0][r])) + xv.x;
    res.y = g * (ov.y + bf2f(tile[cq + 1][r])) + xv.y;
    res.z = g * (ov.z + bf2f(tile[cq + 2][r])) + xv.z;
    res.w = g * (ov.w + bf2f(tile[cq + 3][r])) + xv.w;
    *(float4*)&out[idx] = res;
}

extern "C" void kernel_launch(void* const* d_in, const int* in_sizes, int n_in,
                              void* d_out, int out_size, void* d_ws, size_t ws_size,
                              hipStream_t stream)
{
    const float* x     = (const float*)d_in[0];
    const float* Wq    = (const float*)d_in[1];
    const float* bq    = (const float*)d_in[2];
    const float* Wk    = (const float*)d_in[3];
    const float* bk    = (const float*)d_in[4];
    const float* Wv    = (const float*)d_in[5];
    const float* bv    = (const float*)d_in[6];
    const float* gamma = (const float*)d_in[7];
    float* out = (float*)d_out;

    ushortT* ws = (ushortT*)d_ws;
    const size_t qk_sz  = (size_t)B * CQ * P;   //  4,194,304 bf16
    const size_t v_sz   = (size_t)B * C  * P;   // 33,554,432 bf16
    const size_t att_sz = (size_t)B * P * 256;  // 33,554,432 bf16

    ushortT* qt  = ws;                 // q transposed (b,p,32)
    ushortT* kt  = qt  + qk_sz;        // k transposed (b,p,32)
    ushortT* vb  = kt  + qk_sz;        // v natural (b,c,p)
    ushortT* vto = vb  + v_sz;         // xt -> vto (v transposed) -> outH^T (in place)
    ushortT* att = vto + v_sz;

    ushortT* xt     = vto;                       // overlay: xt dead after proj
    ushortT* Wfrag  = att;                       // overlay: dead after proj
    float*   biasAll = (float*)(att + 81920);

    const size_t needed_bytes = (2 * qk_sz + 2 * v_sz + att_sz) * sizeof(ushortT); // ~218 MB
    if (ws_size < needed_bytes) return;  // canary: zeros out -> absmax ~5.4

    pack_kernel<<<dim3(41), 256, 0, stream>>>(Wq, bq, Wk, bk, Wv, bv, Wfrag, biasAll);
    xt_kernel<<<dim3(P / 32, C / 64, B), 256, 0, stream>>>(x, xt);
    proj_mfma<<<dim3(P / 128, B), 256, 0, stream>>>(xt, Wfrag, biasAll, qt, kt, vb);
    transpose_v_kernel<<<dim3(W / 32, H / 32, B * C), dim3(32, 8), 0, stream>>>(vb, vto);
    eh_mfma<<<dim3(W, B), 256, 0, stream>>>(qt, kt, att);
    ew_sm<<<dim3(H, B), 256, 0, stream>>>(qt, kt, att);
    outh_mfma<<<dim3(2, W, B), 256, 0, stream>>>(vto, att);
    outw_mfma<<<dim3(2, H, B), 256, 0, stream>>>(vb, att, out);
    combine_kernel<<<dim3(W / 32, H / 32, B * C), 256, 0, stream>>>(vto, x, gamma, out);
}